// Round 11
// baseline (192.656 us; speedup 1.0000x reference)
//
#include <hip/hip_runtime.h>
#include <stdint.h>

#define DEVI __device__ __forceinline__

typedef float        f32x4   __attribute__((ext_vector_type(4)));
typedef float        f32x16  __attribute__((ext_vector_type(16)));
typedef __bf16       bf16x8  __attribute__((ext_vector_type(8)));
typedef unsigned short u16x8 __attribute__((ext_vector_type(8)));
typedef uint32_t     u32x2   __attribute__((ext_vector_type(2)));
typedef uint32_t     u32x4   __attribute__((ext_vector_type(4)));

static constexpr int TSEQ   = 2048;
static constexpr int NSTATE = 1024;
static constexpr int NHEAD  = 16;
static constexpr int DHEAD  = 64;
static constexpr int BATCH  = 4;
static constexpr int MROWS  = BATCH * TSEQ;              // 8192
// Q epilogue scale: D^-0.5 * log2(e)  (whole softmax in exp2 domain)
static constexpr float QSCALE = 0.125f * 1.44269504088896340736f;
static constexpr float DEFER_THR = 8.0f * 1.44269504088896340736f;

DEVI unsigned short f2bf(float f) {
  union { float f; uint32_t u; } v; v.f = f;
  return (unsigned short)((v.u + 0x7fffu + ((v.u >> 16) & 1u)) >> 16);
}

DEVI uint32_t cvt_pk_bf16(float lo, float hi) {   // packs {lo,hi} -> 2xbf16 (RNE)
  uint32_t r;
  asm("v_cvt_pk_bf16_f32 %0, %1, %2" : "=v"(r) : "v"(lo), "v"(hi));
  return r;
}
DEVI float fexp2(float x) {                        // bare v_exp_f32 (D = 2^S0)
  float r;
  asm("v_exp_f32 %0, %1" : "=v"(r) : "v"(x));
  return r;
}

DEVI f32x4 mfma16(u16x8 a, u16x8 b, f32x4 c) {
  return __builtin_amdgcn_mfma_f32_16x16x32_bf16(
      __builtin_bit_cast(bf16x8, a), __builtin_bit_cast(bf16x8, b), c, 0, 0, 0);
}
DEVI f32x16 mfma32(u16x8 a, u16x8 b, f32x16 c) {
  return __builtin_amdgcn_mfma_f32_32x32x16_bf16(
      __builtin_bit_cast(bf16x8, a), __builtin_bit_cast(bf16x8, b), c, 0, 0, 0);
}

DEVI void gload_lds16(const void* g, void* l) {
  __builtin_amdgcn_global_load_lds(
      (const __attribute__((address_space(1))) void*)g,
      (__attribute__((address_space(3))) void*)l, 16, 0, 0);
}

// ---------------- f32 -> bf16 conversion: x + 4 weights, one launch ---------
__global__ void cvt_all(const float* __restrict__ x,
                        const float* __restrict__ w0, const float* __restrict__ w1,
                        const float* __restrict__ w2, const float* __restrict__ w3,
                        unsigned short* __restrict__ xb,
                        unsigned short* __restrict__ wb)   // wq..wo contiguous
{
  const int NX = (MROWS * NSTATE) / 4;           // 2^21 float4 groups for x
  const int NW = (NSTATE * NSTATE) / 4;          // 2^18 per weight
  const int total = NX + 4 * NW;
  int i = blockIdx.x * blockDim.x + threadIdx.x;
  const int stride = gridDim.x * blockDim.x;
  for (; i < total; i += stride) {
    const float* src;
    unsigned short* dst;
    int j;
    if (i < NX) { src = x; dst = xb; j = i; }
    else {
      const int k = i - NX, wi = k >> 18;
      src = (wi == 0) ? w0 : (wi == 1) ? w1 : (wi == 2) ? w2 : w3;
      dst = wb + ((size_t)wi << 20);
      j = k & (NW - 1);
    }
    const float4 f = ((const float4*)src)[j];
    ushort4 o;
    o.x = f2bf(f.x); o.y = f2bf(f.y); o.z = f2bf(f.z); o.w = f2bf(f.w);
    ((ushort4*)dst)[j] = o;
  }
}

// ---------------- deep-pipelined GEMM: BM=256, BN=128, BK=64, 8 waves --------
// Triple-buffered LDS (144KB, 1 block/CU), prefetch distance 2, counted
// vmcnt(6) at group end, raw s_barrier (no vmcnt(0) drain), 1 barrier/K-tile.
// Pre-swizzled global source granule keeps gload_lds dests linear; ds_read
// slot XOR gives even 8-words/bank distribution (conflict-free).
// MODE 0: QKV (wi = blockIdx.x>>3; Q*(QSCALE)+bq / K / V+bv -> bf16 scatter)
// MODE 1: out (C = A W^T + bias -> f32 row-major)
template<int MODE>
__global__ __launch_bounds__(512)
void gemm_deep(const unsigned short* __restrict__ A,
               const unsigned short* __restrict__ Wall,
               const float* __restrict__ bq, const float* __restrict__ bv,
               void* __restrict__ out)
{
  constexpr int ASZ = 256 * 64;                  // u16 per A buffer
  constexpr int BSZ = 128 * 64;
  constexpr int NT  = NSTATE / 64;               // 16 K-tiles
  __shared__ __align__(16) unsigned short As[3 * ASZ];
  __shared__ __align__(16) unsigned short Bs[3 * BSZ];

  const int t = threadIdx.x, lane = t & 63, wid = t >> 6;
  const int fr = lane & 15, fq = lane >> 4;
  const int wm = wid >> 1, wn = wid & 1;         // 4x2 waves, 64x64 per wave
  int wi, n0;
  if (MODE == 0) { wi = blockIdx.x >> 3; n0 = (blockIdx.x & 7) * 128; }
  else           { wi = 0;               n0 = blockIdx.x * 128; }
  const int m0 = blockIdx.y * 256;
  const unsigned short* Bw = Wall + ((size_t)wi << 20);

  f32x4 acc[4][4] = {};

  // staging: thread t covers row q*64 + (t>>3), slot t&7; source granule is
  // pre-swizzled so the linear gload_lds dest realizes the XOR layout.
  const int sg = (t & 7) ^ ((t >> 3) & 7);
  const unsigned short* asrc[4];
  const unsigned short* bsrc[2];
  #pragma unroll
  for (int q = 0; q < 4; ++q)
    asrc[q] = A + (size_t)(m0 + q * 64 + (t >> 3)) * NSTATE + sg * 8;
  #pragma unroll
  for (int q = 0; q < 2; ++q)
    bsrc[q] = Bw + (size_t)(n0 + q * 64 + (t >> 3)) * NSTATE + sg * 8;
  const int ldst = t * 8;                        // u16 offset within a q-slice

  // fragment read offsets (u16), lane-constant: slot = (kk*4+fq) ^ (fr&7)
  int aofs[2][4], bofs[2][4];
  #pragma unroll
  for (int kk = 0; kk < 2; ++kk)
    #pragma unroll
    for (int i = 0; i < 4; ++i) {
      const int sl = ((kk * 4 + fq) ^ (fr & 7)) * 8;
      aofs[kk][i] = (wm * 64 + i * 16 + fr) * 64 + sl;
      bofs[kk][i] = (wn * 64 + i * 16 + fr) * 64 + sl;
    }

  #define STAGE(nb, kt)                                              \
    do {                                                             \
      unsigned short* ab_ = As + (nb) * ASZ;                         \
      unsigned short* bb_ = Bs + (nb) * BSZ;                         \
      _Pragma("unroll")                                              \
      for (int q = 0; q < 4; ++q)                                    \
        gload_lds16(asrc[q] + (kt) * 64, ab_ + q * 4096 + ldst);     \
      _Pragma("unroll")                                              \
      for (int q = 0; q < 2; ++q)                                    \
        gload_lds16(bsrc[q] + (kt) * 64, bb_ + q * 4096 + ldst);     \
    } while (0)

  // prologue: stage tiles 0,1 -> bufs 0,1; wait for tile 0 (6 newest may fly)
  STAGE(0, 0);
  STAGE(1, 1);
  asm volatile("s_waitcnt vmcnt(6)" ::: "memory");
  __builtin_amdgcn_sched_barrier(0);
  __builtin_amdgcn_s_barrier();
  __builtin_amdgcn_sched_barrier(0);

  int cur = 0;
  for (int kt = 0; kt < NT; ++kt) {
    const unsigned short* ab = As + cur * ASZ;
    const unsigned short* bb = Bs + cur * BSZ;
    const bool pre = (kt + 2) < NT;
    int nb = cur + 2; if (nb >= 3) nb -= 3;
    if (pre) STAGE(nb, kt + 2);                  // issue-early (T14)

    #pragma unroll
    for (int kk = 0; kk < 2; ++kk) {
      u16x8 af[4], bf[4];
      #pragma unroll
      for (int i = 0; i < 4; ++i) af[i] = *(const u16x8*)(ab + aofs[kk][i]);
      #pragma unroll
      for (int i = 0; i < 4; ++i) bf[i] = *(const u16x8*)(bb + bofs[kk][i]);
      __builtin_amdgcn_s_setprio(1);
      #pragma unroll
      for (int i = 0; i < 4; ++i)
        #pragma unroll
        for (int j = 0; j < 4; ++j)
          acc[i][j] = mfma16(af[i], bf[j], acc[i][j]);
      __builtin_amdgcn_s_setprio(0);
    }

    // group end: allow only this group's 6 loads outstanding -> tile kt+1's
    // loads (issued last group) have landed before any wave reads them.
    if (pre) asm volatile("s_waitcnt vmcnt(6)" ::: "memory");
    else     asm volatile("s_waitcnt vmcnt(0)" ::: "memory");
    __builtin_amdgcn_sched_barrier(0);
    __builtin_amdgcn_s_barrier();
    __builtin_amdgcn_sched_barrier(0);
    cur += 1; if (cur == 3) cur = 0;
  }
  #undef STAGE

  if (MODE == 0) {
    unsigned short* Cq = (unsigned short*)out + ((size_t)wi << 23);
    const int h = (n0 >> 6) + wn;                // head, uniform per wave
    #pragma unroll
    for (int j = 0; j < 4; ++j) {
      const int d = j * 16 + fr;                 // 0..63
      const int ncol = n0 + wn * 64 + d;
      const float bj = (wi == 1) ? 0.0f : ((wi == 0) ? bq[ncol] : bv[ncol]);
      #pragma unroll
      for (int i = 0; i < 4; ++i) {
        #pragma unroll
        for (int r = 0; r < 4; ++r) {
          const int row = m0 + wm * 64 + i * 16 + fq * 4 + r;
          const int bb_ = row >> 11, tt = row & (TSEQ - 1);
          float v = acc[i][j][r] + bj;
          if (wi == 0) v *= QSCALE;
          Cq[(((size_t)(bb_ * NHEAD + h)) * TSEQ + tt) * DHEAD + d] = f2bf(v);
        }
      }
    }
  } else {
    float* Co = (float*)out;
    #pragma unroll
    for (int j = 0; j < 4; ++j) {
      const int col = n0 + wn * 64 + j * 16 + fr;
      const float bj = bq[col];
      #pragma unroll
      for (int i = 0; i < 4; ++i) {
        const int row0 = m0 + wm * 64 + i * 16 + fq * 4;
        #pragma unroll
        for (int r = 0; r < 4; ++r)
          Co[(size_t)(row0 + r) * NSTATE + col] = acc[i][j][r] + bj;
      }
    }
  }
}

// ---------------- flash attention: 4 waves x 32 q-rows, 32x32x16 MFMA --------
// (unchanged from round 10: 86 us, VGPR 92)
__global__ __launch_bounds__(256)
void flash_attn(const unsigned short* __restrict__ Qg,
                const unsigned short* __restrict__ Kg,
                const unsigned short* __restrict__ Vg,
                unsigned short* __restrict__ O)
{
  const int bh = blockIdx.x;
  const int qb = 15 - (int)blockIdx.y;
  const int b  = bh >> 4, h = bh & 15;
  const int t  = threadIdx.x, lane = t & 63, w = t >> 6;   // w: 0..3
  const int lq = lane & 31, hi = lane >> 5;
  const size_t hoff = (size_t)bh * TSEQ * DHEAD;
  const unsigned short* Qp = Qg + hoff;
  const unsigned short* Kp = Kg + hoff;
  const unsigned short* Vp = Vg + hoff;

  __shared__ __align__(16) unsigned short Kb[2][64 * 64];
  __shared__ __align__(16) unsigned short Vb[2][64 * 64];   // V^T, swizzled octets

  const int qw   = qb * 128 + w * 32;        // wave's first q-row
  const int qrow = qw + lq;                  // this lane's q-row

  u16x8 qf[4];                               // Q[qrow][16c + hi*8 .. +7]
  #pragma unroll
  for (int c = 0; c < 4; ++c)
    qf[c] = *(const u16x8*)(Qp + (size_t)qrow * DHEAD + c * 16 + hi * 8);

  f32x16 oacc[2] = {};                       // O^T: col=q(lane), rows d-pattern
  float m_r = -1e30f, l_r = 0.0f;            // exp2-domain softmax state

  // hoisted per-lane LDS byte offsets (constant across iterations)
  const char* KbB = (const char*)&Kb[0][0];
  const char* VbB = (const char*)&Vb[0][0];
  int koff[4], voff[4];
  #pragma unroll
  for (int c = 0; c < 4; ++c) {
    koff[c] = lq * 128 + (((2 * c + hi) ^ (lane & 7)) << 4);
    voff[c] = lq * 128 + (((2 * c + hi) ^ (lq & 7)) << 4);
  }

  // staging assignments (256 threads)
  const int skr = t >> 2, skg = t & 3;       // K: row skr, 32B chunk skg
  const int svk2 = (t & 31) * 2;             // V: two adjacent k per thread
  const int svd  = (t >> 5) * 8;             // 8 d's per thread

  const int nt = (qb + 1) * 2;

  #define STAGE_V(buf, va, vb)                                              \
    do {                                                                    \
      const u32x4 vau = __builtin_bit_cast(u32x4, va);                      \
      const u32x4 vbu = __builtin_bit_cast(u32x4, vb);                      \
      _Pragma("unroll")                                                     \
      for (int j = 0; j < 4; ++j) {                                         \
        const uint32_t pe = __builtin_amdgcn_perm(vbu[j], vau[j], 0x05040100); \
        const uint32_t po = __builtin_amdgcn_perm(vbu[j], vau[j], 0x07060302); \
        *(uint32_t*)(&Vb[buf][(svd + 2 * j) * 64 + (svk2 ^ ((2 * j) << 3))]) = pe; \
        *(uint32_t*)(&Vb[buf][(svd + 2 * j + 1) * 64 + (svk2 ^ ((2 * j + 1) << 3))]) = po; \
      }                                                                     \
    } while (0)

  { // prologue: stage tile 0
    const u16x8 kr0 = *(const u16x8*)(Kp + (size_t)skr * DHEAD + skg * 16);
    const u16x8 kr1 = *(const u16x8*)(Kp + (size_t)skr * DHEAD + skg * 16 + 8);
    const u16x8 va  = *(const u16x8*)(Vp + (size_t)svk2 * DHEAD + svd);
    const u16x8 vb  = *(const u16x8*)(Vp + (size_t)(svk2 + 1) * DHEAD + svd);
    *(u16x8*)(&Kb[0][skr * 64 + (((skg * 2)     ^ (skr & 7)) << 3)]) = kr0;
    *(u16x8*)(&Kb[0][skr * 64 + (((skg * 2 + 1) ^ (skr & 7)) << 3)]) = kr1;
    STAGE_V(0, va, vb);
  }
  __syncthreads();

  for (int kt = 0; kt < nt; ++kt) {
    const int k0 = kt * 64;
    const int curB = (kt & 1) << 13;         // byte offset of current buffer
    const bool pre = (kt + 1 < nt);
    u16x8 krn0, krn1, van, vbn;
    if (pre) {                               // T14: issue next-tile loads early
      const int k0n = k0 + 64;
      krn0 = *(const u16x8*)(Kp + (size_t)(k0n + skr) * DHEAD + skg * 16);
      krn1 = *(const u16x8*)(Kp + (size_t)(k0n + skr) * DHEAD + skg * 16 + 8);
      van  = *(const u16x8*)(Vp + (size_t)(k0n + svk2) * DHEAD + svd);
      vbn  = *(const u16x8*)(Vp + (size_t)(k0n + svk2 + 1) * DHEAD + svd);
    }

    if (k0 < qw + 32) {                      // wave-active (not fully masked)
      // ---- QK^T: S^T[k][q], 2 x (32k) tiles, 4 K=16 chunks over D=64
      f32x16 s[2];
      __builtin_amdgcn_s_setprio(1);
      #pragma unroll
      for (int t32 = 0; t32 < 2; ++t32) {
        if (k0 + t32 * 32 < qw + 32) {
          f32x16 z = {};
          #pragma unroll
          for (int c = 0; c < 4; ++c) {
            const u16x8 kf = *(const u16x8*)(KbB + curB + koff[c] + t32 * 4096);
            z = mfma32(kf, qf[c], z);
          }
          s[t32] = z;
        } else {
          #pragma unroll
          for (int r = 0; r < 16; ++r) s[t32][r] = -1e30f;
        }
      }
      __builtin_amdgcn_s_setprio(0);
      if (k0 + 63 > qw) {                    // crossing: element causal mask
        #pragma unroll
        for (int t32 = 0; t32 < 2; ++t32)
          #pragma unroll
          for (int r = 0; r < 16; ++r) {
            const int kk = k0 + t32 * 32 + (r & 3) + 8 * (r >> 2) + 4 * hi;
            if (kk > qrow) s[t32][r] = -1e30f;
          }
      }

      // ---- softmax max: max3 tree + one cross-half shuffle
      float mx = fmaxf(s[0][14], s[0][15]);
      #pragma unroll
      for (int r = 0; r < 14; r += 2) mx = fmaxf(fmaxf(mx, s[0][r]), s[0][r + 1]);
      #pragma unroll
      for (int r = 0; r < 16; r += 2) mx = fmaxf(fmaxf(mx, s[1][r]), s[1][r + 1]);
      mx = fmaxf(mx, __shfl_xor(mx, 32));

      if (__any(mx > m_r + DEFER_THR)) {     // T13 defer-max
        const float mnew = fmaxf(m_r, mx);
        const float corr = fexp2(m_r - mnew);
        #pragma unroll
        for (int ds = 0; ds < 2; ++ds)
          #pragma unroll
          for (int r = 0; r < 16; ++r) oacc[ds][r] *= corr;
        l_r *= corr;
        m_r = mnew;
      }

      // ---- P = exp2(S - m): cvt_pk packing; l-sum in f32 (pre-rounding)
      float ps = 0.0f;
      uint32_t pk[2][8];
      #pragma unroll
      for (int t32 = 0; t32 < 2; ++t32)
        #pragma unroll
        for (int m2 = 0; m2 < 8; ++m2) {
          const float pa = fexp2(s[t32][2 * m2]     - m_r);
          const float pb = fexp2(s[t32][2 * m2 + 1] - m_r);
          ps += pa + pb;
          pk[t32][m2] = cvt_pk_bf16(pa, pb);
        }
      ps += __shfl_xor(ps, 32);
      l_r += ps;

      // ---- P frags: half-exchange via permlane32_swap (T12)
      uint32_t pf[2][2][4];
      #pragma unroll
      for (int t32 = 0; t32 < 2; ++t32)
        #pragma unroll
        for (int hf = 0; hf < 2; ++hf) {
          const u32x2 r02 = __builtin_amdgcn_permlane32_swap(
              pk[t32][hf * 4 + 0], pk[t32][hf * 4 + 2], false, false);
          const u32x2 r13 = __builtin_amdgcn_permlane32_swap(
              pk[t32][hf * 4 + 1], pk[t32][hf * 4 + 3], false, false);
          pf[t32][hf][0] = r02.x; pf[t32][hf][2] = r02.y;
          pf[t32][hf][1] = r13.x; pf[t32][hf][3] = r13.y;
        }

      // ---- PV: O^T += V^T * P^T, 4 K=16 chunks over the 64 k
      __builtin_amdgcn_s_setprio(1);
      #pragma unroll
      for (int c = 0; c < 4; ++c) {
        if (k0 + 16 * c < qw + 32) {         // wave-uniform causal chunk skip
          const u32x4 pw = {pf[c >> 1][c & 1][0], pf[c >> 1][c & 1][1],
                            pf[c >> 1][c & 1][2], pf[c >> 1][c & 1][3]};
          const u16x8 pv = __builtin_bit_cast(u16x8, pw);
          #pragma unroll
          for (int ds = 0; ds < 2; ++ds) {
            const u16x8 vf = *(const u16x8*)(VbB + curB + voff[c] + ds * 4096);
            oacc[ds] = mfma32(vf, pv, oacc[ds]);
          }
        }
      }
      __builtin_amdgcn_s_setprio(0);
    }

    if (pre) {                               // write-late into the other buffer
      const int nb = (kt & 1) ^ 1;
      *(u16x8*)(&Kb[nb][skr * 64 + (((skg * 2)     ^ (skr & 7)) << 3)]) = krn0;
      *(u16x8*)(&Kb[nb][skr * 64 + (((skg * 2 + 1) ^ (skr & 7)) << 3)]) = krn1;
      STAGE_V(nb, van, vbn);
    }
    __syncthreads();
  }

  // ---- epilogue: O[q][d] = oacc/l, paired u32 stores
  const float inv = 1.0f / l_r;
  const size_t base = ((size_t)(b * TSEQ + qrow)) * NSTATE + h * DHEAD;
  #pragma unroll
  for (int ds = 0; ds < 2; ++ds)
    #pragma unroll
    for (int m2 = 0; m2 < 8; ++m2) {
      const int d = ds * 32 + 2 * (m2 & 1) + 8 * (m2 >> 1) + 4 * hi;
      *(uint32_t*)(O + base + d) =
          cvt_pk_bf16(oacc[ds][2 * m2] * inv, oacc[ds][2 * m2 + 1] * inv);
    }
  #undef STAGE_V
}

// ---------------- launcher ----------------
extern "C" void kernel_launch(void* const* d_in, const int* in_sizes, int n_in,
                              void* d_out, int out_size, void* d_ws, size_t ws_size,
                              hipStream_t stream)
{
  (void)in_sizes; (void)n_in; (void)out_size; (void)ws_size;
  const float* x  = (const float*)d_in[0];
  const float* Wq = (const float*)d_in[2];
  const float* bq = (const float*)d_in[3];
  const float* Wk = (const float*)d_in[4];
  const float* Wv = (const float*)d_in[5];
  const float* bv = (const float*)d_in[6];
  const float* Wo = (const float*)d_in[7];
  const float* bo = (const float*)d_in[8];

  char* ws = (char*)d_ws;
  unsigned short* xb  = (unsigned short*)(ws);               // 16MB (reused for attn out)
  unsigned short* wqb = (unsigned short*)(ws + (16u << 20)); // Wq,Wk,Wv,Wo contiguous
  unsigned short* wob = wqb + (3u << 20);
  unsigned short* qb_ = (unsigned short*)(ws + (24u << 20)); // Q,K,V contiguous 16MB each
  unsigned short* kb_ = (unsigned short*)(ws + (40u << 20));
  unsigned short* vb_ = (unsigned short*)(ws + (56u << 20));

  cvt_all<<<2048, 256, 0, stream>>>(x, Wq, Wk, Wv, Wo, xb, wqb);

  gemm_deep<0><<<dim3(24, MROWS / 256), 512, 0, stream>>>(xb, wqb, bq, bv, qb_);

  flash_attn<<<dim3(BATCH * NHEAD, 16), 256, 0, stream>>>(qb_, kb_, vb_, xb);

  gemm_deep<1><<<dim3(NSTATE / 128, MROWS / 256), 512, 0, stream>>>(xb, wob, bo, nullptr, d_out);
}

// Round 12
// 189.347 us; speedup vs baseline: 1.0175x; 1.0175x over previous
//
#include <hip/hip_runtime.h>
#include <stdint.h>

#define DEVI __device__ __forceinline__

typedef float        f32x2   __attribute__((ext_vector_type(2)));
typedef float        f32x4   __attribute__((ext_vector_type(4)));
typedef float        f32x16  __attribute__((ext_vector_type(16)));
typedef __bf16       bf16x8  __attribute__((ext_vector_type(8)));
typedef unsigned short u16x8 __attribute__((ext_vector_type(8)));
typedef uint32_t     u32x2   __attribute__((ext_vector_type(2)));
typedef uint32_t     u32x4   __attribute__((ext_vector_type(4)));

static constexpr int TSEQ   = 2048;
static constexpr int NSTATE = 1024;
static constexpr int NHEAD  = 16;
static constexpr int DHEAD  = 64;
static constexpr int BATCH  = 4;
static constexpr int MROWS  = BATCH * TSEQ;              // 8192
// Q epilogue scale: D^-0.5 * log2(e)  (whole softmax in exp2 domain)
static constexpr float QSCALE = 0.125f * 1.44269504088896340736f;
static constexpr float DEFER_THR = 8.0f * 1.44269504088896340736f;

DEVI unsigned short f2bf(float f) {
  union { float f; uint32_t u; } v; v.f = f;
  return (unsigned short)((v.u + 0x7fffu + ((v.u >> 16) & 1u)) >> 16);
}

DEVI uint32_t cvt_pk_bf16(float lo, float hi) {   // packs {lo,hi} -> 2xbf16 (RNE)
  uint32_t r;
  asm("v_cvt_pk_bf16_f32 %0, %1, %2" : "=v"(r) : "v"(lo), "v"(hi));
  return r;
}
DEVI float fexp2(float x) {                        // bare v_exp_f32 (D = 2^S0)
  float r;
  asm("v_exp_f32 %0, %1" : "=v"(r) : "v"(x));
  return r;
}

DEVI f32x4 mfma16(u16x8 a, u16x8 b, f32x4 c) {
  return __builtin_amdgcn_mfma_f32_16x16x32_bf16(
      __builtin_bit_cast(bf16x8, a), __builtin_bit_cast(bf16x8, b), c, 0, 0, 0);
}
DEVI f32x16 mfma32(u16x8 a, u16x8 b, f32x16 c) {
  return __builtin_amdgcn_mfma_f32_32x32x16_bf16(
      __builtin_bit_cast(bf16x8, a), __builtin_bit_cast(bf16x8, b), c, 0, 0, 0);
}

DEVI void gload_lds16(const void* g, void* l) {
  __builtin_amdgcn_global_load_lds(
      (const __attribute__((address_space(1))) void*)g,
      (__attribute__((address_space(3))) void*)l, 16, 0, 0);
}

// ---------------- f32 -> bf16 conversion: x + 4 weights, one launch ---------
__global__ void cvt_all(const float* __restrict__ x,
                        const float* __restrict__ w0, const float* __restrict__ w1,
                        const float* __restrict__ w2, const float* __restrict__ w3,
                        unsigned short* __restrict__ xb,
                        unsigned short* __restrict__ wb)   // wq..wo contiguous
{
  const int NX = (MROWS * NSTATE) / 4;           // 2^21 float4 groups for x
  const int NW = (NSTATE * NSTATE) / 4;          // 2^18 per weight
  const int total = NX + 4 * NW;
  int i = blockIdx.x * blockDim.x + threadIdx.x;
  const int stride = gridDim.x * blockDim.x;
  for (; i < total; i += stride) {
    const float* src;
    unsigned short* dst;
    int j;
    if (i < NX) { src = x; dst = xb; j = i; }
    else {
      const int k = i - NX, wi = k >> 18;
      src = (wi == 0) ? w0 : (wi == 1) ? w1 : (wi == 2) ? w2 : w3;
      dst = wb + ((size_t)wi << 20);
      j = k & (NW - 1);
    }
    const float4 f = ((const float4*)src)[j];
    ushort4 o;
    o.x = f2bf(f.x); o.y = f2bf(f.y); o.z = f2bf(f.z); o.w = f2bf(f.w);
    ((ushort4*)dst)[j] = o;
  }
}

// ---------------- fused QKV GEMM: grid (24, 64); x -> {weight, n-tile} --------
// wi 0: Q = (acc+bq)*QSCALE ; wi 1: K = acc ; wi 2: V = acc+bv
__global__ __launch_bounds__(256)
void gemm_qkv(const unsigned short* __restrict__ A,
              const unsigned short* __restrict__ Wqkv,
              const float* __restrict__ bq, const float* __restrict__ bv,
              unsigned short* __restrict__ Oqkv)
{
  __shared__ __align__(16) unsigned short As[128 * 32];
  __shared__ __align__(16) unsigned short Bs[128 * 32];
  const int t  = threadIdx.x;
  const int l  = t & 63, w = t >> 6;
  const int fr = l & 15, fq = l >> 4;
  const int wi = blockIdx.x >> 3;
  const int n0 = (blockIdx.x & 7) * 128;
  const int m0 = blockIdx.y * 128;
  const int wm = (w & 1) * 64, wn = (w >> 1) * 64;
  const unsigned short* Bw = Wqkv + ((size_t)wi << 20);
  unsigned short* Cq = Oqkv + ((size_t)wi << 23);

  f32x4 acc[4][4] = {};

  const int sr = t >> 2;
  const int sc = (t & 3) * 8;
  const unsigned short* ag = A  + (size_t)(m0 + sr) * NSTATE + sc;
  const unsigned short* bg = Bw + (size_t)(n0 + sr) * NSTATE + sc;
  unsigned short* lA0 = As + t * 8;
  unsigned short* lA1 = As + 2048 + t * 8;
  unsigned short* lB0 = Bs + t * 8;
  unsigned short* lB1 = Bs + 2048 + t * 8;

  for (int kt = 0; kt < NSTATE / 32; ++kt) {
    const int ko = kt * 32;
    gload_lds16(ag + ko,               lA0);
    gload_lds16(ag + 64 * NSTATE + ko, lA1);
    gload_lds16(bg + ko,               lB0);
    gload_lds16(bg + 64 * NSTATE + ko, lB1);
    __syncthreads();

    u16x8 a[4], b[4];
    #pragma unroll
    for (int i = 0; i < 4; ++i)
      a[i] = *(const u16x8*)(As + (wm + i * 16 + fr) * 32 + fq * 8);
    #pragma unroll
    for (int j = 0; j < 4; ++j)
      b[j] = *(const u16x8*)(Bs + (wn + j * 16 + fr) * 32 + fq * 8);
    #pragma unroll
    for (int i = 0; i < 4; ++i)
      #pragma unroll
      for (int j = 0; j < 4; ++j)
        acc[i][j] = mfma16(a[i], b[j], acc[i][j]);
    __syncthreads();
  }

  const int h = (n0 + wn) >> 6;
  #pragma unroll
  for (int j = 0; j < 4; ++j) {
    const int d = j * 16 + fr;
    const float bj = (wi == 1) ? 0.0f
                   : ((wi == 0) ? bq[n0 + wn + d] : bv[n0 + wn + d]);
    #pragma unroll
    for (int i = 0; i < 4; ++i) {
      #pragma unroll
      for (int r = 0; r < 4; ++r) {
        const int row = m0 + wm + i * 16 + fq * 4 + r;
        const int bb = row >> 11, tt = row & (TSEQ - 1);
        float v = acc[i][j][r] + bj;
        if (wi == 0) v *= QSCALE;
        Cq[(((size_t)(bb * NHEAD + h)) * TSEQ + tt) * DHEAD + d] = f2bf(v);
      }
    }
  }
}

// ---------------- output projection GEMM: C = A W^T + bo (f32 out) ----------
__global__ __launch_bounds__(256)
void gemm_out(const unsigned short* __restrict__ A,
              const unsigned short* __restrict__ Bw,
              const float* __restrict__ bias,
              float* __restrict__ Co)
{
  __shared__ __align__(16) unsigned short As[128 * 32];
  __shared__ __align__(16) unsigned short Bs[128 * 32];
  const int t  = threadIdx.x;
  const int l  = t & 63, w = t >> 6;
  const int fr = l & 15, fq = l >> 4;
  const int m0 = blockIdx.y * 128, n0 = blockIdx.x * 128;
  const int wm = (w & 1) * 64, wn = (w >> 1) * 64;

  f32x4 acc[4][4] = {};

  const int sr = t >> 2;
  const int sc = (t & 3) * 8;
  const unsigned short* ag = A  + (size_t)(m0 + sr) * NSTATE + sc;
  const unsigned short* bg = Bw + (size_t)(n0 + sr) * NSTATE + sc;
  unsigned short* lA0 = As + t * 8;
  unsigned short* lA1 = As + 2048 + t * 8;
  unsigned short* lB0 = Bs + t * 8;
  unsigned short* lB1 = Bs + 2048 + t * 8;

  for (int kt = 0; kt < NSTATE / 32; ++kt) {
    const int ko = kt * 32;
    gload_lds16(ag + ko,               lA0);
    gload_lds16(ag + 64 * NSTATE + ko, lA1);
    gload_lds16(bg + ko,               lB0);
    gload_lds16(bg + 64 * NSTATE + ko, lB1);
    __syncthreads();

    u16x8 a[4], b[4];
    #pragma unroll
    for (int i = 0; i < 4; ++i)
      a[i] = *(const u16x8*)(As + (wm + i * 16 + fr) * 32 + fq * 8);
    #pragma unroll
    for (int j = 0; j < 4; ++j)
      b[j] = *(const u16x8*)(Bs + (wn + j * 16 + fr) * 32 + fq * 8);
    #pragma unroll
    for (int i = 0; i < 4; ++i)
      #pragma unroll
      for (int j = 0; j < 4; ++j)
        acc[i][j] = mfma16(a[i], b[j], acc[i][j]);
    __syncthreads();
  }

  #pragma unroll
  for (int j = 0; j < 4; ++j) {
    const int col = n0 + wn + j * 16 + fr;
    const float bj = bias[col];
    #pragma unroll
    for (int i = 0; i < 4; ++i) {
      const int row0 = m0 + wm + i * 16 + fq * 4;
      #pragma unroll
      for (int r = 0; r < 4; ++r)
        Co[(size_t)(row0 + r) * NSTATE + col] = acc[i][j][r] + bj;
    }
  }
}

// ---------------- flash attention: 4 waves x 32 q-rows, 32x32x16 MFMA --------
// grid (64 heads, 16 q-tiles), block 256; qb = 15 - y (longest first).
// KVBLK=64, K/V double-buffered LDS (16B-XOR swizzle). K staged via
// global_load_lds with PRE-SWIZZLED per-lane source (linear LDS dest);
// V reg-staged with v_perm transpose-pack (T14 issue-early / write-late).
// S^T = mfma32(K, Q); exp2-domain softmax; cvt_pk + permlane32_swap for P;
// ps/rescale vectorized for packed-f32 (v_pk_add/v_pk_mul).
__global__ __launch_bounds__(256)
void flash_attn(const unsigned short* __restrict__ Qg,
                const unsigned short* __restrict__ Kg,
                const unsigned short* __restrict__ Vg,
                unsigned short* __restrict__ O)
{
  const int bh = blockIdx.x;
  const int qb = 15 - (int)blockIdx.y;
  const int b  = bh >> 4, h = bh & 15;
  const int t  = threadIdx.x, lane = t & 63, w = t >> 6;   // w: 0..3
  const int lq = lane & 31, hi = lane >> 5;
  const size_t hoff = (size_t)bh * TSEQ * DHEAD;
  const unsigned short* Qp = Qg + hoff;
  const unsigned short* Kp = Kg + hoff;
  const unsigned short* Vp = Vg + hoff;

  __shared__ __align__(16) unsigned short Kb[2][64 * 64];
  __shared__ __align__(16) unsigned short Vb[2][64 * 64];   // V^T, swizzled octets

  const int qw   = qb * 128 + w * 32;        // wave's first q-row
  const int qrow = qw + lq;                  // this lane's q-row

  u16x8 qf[4];                               // Q[qrow][16c + hi*8 .. +7]
  #pragma unroll
  for (int c = 0; c < 4; ++c)
    qf[c] = *(const u16x8*)(Qp + (size_t)qrow * DHEAD + c * 16 + hi * 8);

  f32x16 oacc[2] = {};                       // O^T: col=q(lane), rows d-pattern
  float m_r = -1e30f, l_r = 0.0f;            // exp2-domain softmax state

  // hoisted per-lane LDS byte offsets (constant across iterations)
  const char* KbB = (const char*)&Kb[0][0];
  const char* VbB = (const char*)&Vb[0][0];
  int koff[4], voff[4];
  #pragma unroll
  for (int c = 0; c < 4; ++c) {
    koff[c] = lq * 128 + (((2 * c + hi) ^ (lane & 7)) << 4);
    voff[c] = lq * 128 + (((2 * c + hi) ^ (lq & 7)) << 4);
  }

  // K staging: gload_lds, linear dest (t*16B), pre-swizzled global source.
  // dest row r = t>>3 (+32 for 2nd call), granule g = t&7 holds K col-octet
  // g ^ (r&7)  ==  the XOR layout the koff[] reads expect.
  const unsigned short* ksrcA =
      Kp + (size_t)(t >> 3) * DHEAD + (((t & 7) ^ ((t >> 3) & 7)) << 3);
  const unsigned short* ksrcB = ksrcA + 32 * DHEAD;
  unsigned short* kdstA0 = &Kb[0][0] + t * 8;
  unsigned short* kdstB0 = &Kb[0][0] + 2048 + t * 8;

  // V staging assignments (reg + v_perm transpose-pack)
  const int svk2 = (t & 31) * 2;             // two adjacent k per thread
  const int svd  = (t >> 5) * 8;             // 8 d's per thread

  const int nt = (qb + 1) * 2;

  #define STAGE_V(buf, va, vb)                                              \
    do {                                                                    \
      const u32x4 vau = __builtin_bit_cast(u32x4, va);                      \
      const u32x4 vbu = __builtin_bit_cast(u32x4, vb);                      \
      _Pragma("unroll")                                                     \
      for (int j = 0; j < 4; ++j) {                                         \
        const uint32_t pe = __builtin_amdgcn_perm(vbu[j], vau[j], 0x05040100); \
        const uint32_t po = __builtin_amdgcn_perm(vbu[j], vau[j], 0x07060302); \
        *(uint32_t*)(&Vb[buf][(svd + 2 * j) * 64 + (svk2 ^ ((2 * j) << 3))]) = pe; \
        *(uint32_t*)(&Vb[buf][(svd + 2 * j + 1) * 64 + (svk2 ^ ((2 * j + 1) << 3))]) = po; \
      }                                                                     \
    } while (0)

  { // prologue: stage tile 0
    gload_lds16(ksrcA, kdstA0);
    gload_lds16(ksrcB, kdstB0);
    const u16x8 va = *(const u16x8*)(Vp + (size_t)svk2 * DHEAD + svd);
    const u16x8 vb = *(const u16x8*)(Vp + (size_t)(svk2 + 1) * DHEAD + svd);
    STAGE_V(0, va, vb);
  }
  __syncthreads();

  for (int kt = 0; kt < nt; ++kt) {
    const int k0 = kt * 64;
    const int curB = (kt & 1) << 13;         // byte offset of current buffer
    const bool pre = (kt + 1 < nt);
    u16x8 van, vbn;
    if (pre) {                               // T14: issue next-tile loads early
      const int k0n = k0 + 64;
      const int nb = (kt & 1) ^ 1;
      gload_lds16(ksrcA + (size_t)k0n * DHEAD, kdstA0 + nb * 4096);
      gload_lds16(ksrcB + (size_t)k0n * DHEAD, kdstB0 + nb * 4096);
      van = *(const u16x8*)(Vp + (size_t)(k0n + svk2) * DHEAD + svd);
      vbn = *(const u16x8*)(Vp + (size_t)(k0n + svk2 + 1) * DHEAD + svd);
    }

    if (k0 < qw + 32) {                      // wave-active (not fully masked)
      // ---- QK^T: S^T[k][q], 2 x (32k) tiles, 4 K=16 chunks over D=64
      f32x16 s[2];
      __builtin_amdgcn_s_setprio(1);
      #pragma unroll
      for (int t32 = 0; t32 < 2; ++t32) {
        if (k0 + t32 * 32 < qw + 32) {
          f32x16 z = {};
          #pragma unroll
          for (int c = 0; c < 4; ++c) {
            const u16x8 kf = *(const u16x8*)(KbB + curB + koff[c] + t32 * 4096);
            z = mfma32(kf, qf[c], z);
          }
          s[t32] = z;
        } else {
          #pragma unroll
          for (int r = 0; r < 16; ++r) s[t32][r] = -1e30f;
        }
      }
      __builtin_amdgcn_s_setprio(0);
      if (k0 + 63 > qw) {                    // crossing: element causal mask
        #pragma unroll
        for (int t32 = 0; t32 < 2; ++t32)
          #pragma unroll
          for (int r = 0; r < 16; ++r) {
            const int kk = k0 + t32 * 32 + (r & 3) + 8 * (r >> 2) + 4 * hi;
            if (kk > qrow) s[t32][r] = -1e30f;
          }
      }

      // ---- softmax max: max3 tree + one cross-half shuffle
      float mx = fmaxf(s[0][14], s[0][15]);
      #pragma unroll
      for (int r = 0; r < 14; r += 2) mx = fmaxf(fmaxf(mx, s[0][r]), s[0][r + 1]);
      #pragma unroll
      for (int r = 0; r < 16; r += 2) mx = fmaxf(fmaxf(mx, s[1][r]), s[1][r + 1]);
      mx = fmaxf(mx, __shfl_xor(mx, 32));

      if (__any(mx > m_r + DEFER_THR)) {     // T13 defer-max
        const float mnew = fmaxf(m_r, mx);
        const float corr = fexp2(m_r - mnew);
        #pragma unroll
        for (int ds = 0; ds < 2; ++ds)
          oacc[ds] *= corr;                  // vector op -> v_pk_mul_f32
        l_r *= corr;
        m_r = mnew;
      }

      // ---- P = exp2(S - m): cvt_pk packing; l-sum vectorized (pk_add)
      f32x2 ps2 = {0.0f, 0.0f};
      uint32_t pk[2][8];
      #pragma unroll
      for (int t32 = 0; t32 < 2; ++t32)
        #pragma unroll
        for (int m2 = 0; m2 < 8; ++m2) {
          const float pa = fexp2(s[t32][2 * m2]     - m_r);
          const float pb = fexp2(s[t32][2 * m2 + 1] - m_r);
          ps2 += (f32x2){pa, pb};            // vector op -> v_pk_add_f32
          pk[t32][m2] = cvt_pk_bf16(pa, pb);
        }
      float ps = ps2[0] + ps2[1];
      ps += __shfl_xor(ps, 32);
      l_r += ps;

      // ---- P frags: half-exchange via permlane32_swap (T12)
      uint32_t pf[2][2][4];
      #pragma unroll
      for (int t32 = 0; t32 < 2; ++t32)
        #pragma unroll
        for (int hf = 0; hf < 2; ++hf) {
          const u32x2 r02 = __builtin_amdgcn_permlane32_swap(
              pk[t32][hf * 4 + 0], pk[t32][hf * 4 + 2], false, false);
          const u32x2 r13 = __builtin_amdgcn_permlane32_swap(
              pk[t32][hf * 4 + 1], pk[t32][hf * 4 + 3], false, false);
          pf[t32][hf][0] = r02.x; pf[t32][hf][2] = r02.y;
          pf[t32][hf][1] = r13.x; pf[t32][hf][3] = r13.y;
        }

      // ---- PV: O^T += V^T * P^T, 4 K=16 chunks over the 64 k
      __builtin_amdgcn_s_setprio(1);
      #pragma unroll
      for (int c = 0; c < 4; ++c) {
        if (k0 + 16 * c < qw + 32) {         // wave-uniform causal chunk skip
          const u32x4 pw = {pf[c >> 1][c & 1][0], pf[c >> 1][c & 1][1],
                            pf[c >> 1][c & 1][2], pf[c >> 1][c & 1][3]};
          const u16x8 pv = __builtin_bit_cast(u16x8, pw);
          #pragma unroll
          for (int ds = 0; ds < 2; ++ds) {
            const u16x8 vf = *(const u16x8*)(VbB + curB + voff[c] + ds * 4096);
            oacc[ds] = mfma32(vf, pv, oacc[ds]);
          }
        }
      }
      __builtin_amdgcn_s_setprio(0);
    }

    if (pre) {                               // write V late into the other buffer
      const int nb = (kt & 1) ^ 1;
      STAGE_V(nb, van, vbn);
    }
    __syncthreads();                         // drains vmcnt: K gload_lds landed
  }

  // ---- epilogue: O[q][d] = oacc/l, paired u32 stores
  const float inv = 1.0f / l_r;
  const size_t base = ((size_t)(b * TSEQ + qrow)) * NSTATE + h * DHEAD;
  #pragma unroll
  for (int ds = 0; ds < 2; ++ds)
    #pragma unroll
    for (int m2 = 0; m2 < 8; ++m2) {
      const int d = ds * 32 + 2 * (m2 & 1) + 8 * (m2 >> 1) + 4 * hi;
      *(uint32_t*)(O + base + d) =
          cvt_pk_bf16(oacc[ds][2 * m2] * inv, oacc[ds][2 * m2 + 1] * inv);
    }
  #undef STAGE_V
}

// ---------------- launcher ----------------
extern "C" void kernel_launch(void* const* d_in, const int* in_sizes, int n_in,
                              void* d_out, int out_size, void* d_ws, size_t ws_size,
                              hipStream_t stream)
{
  (void)in_sizes; (void)n_in; (void)out_size; (void)ws_size;
  const float* x  = (const float*)d_in[0];
  const float* Wq = (const float*)d_in[2];
  const float* bq = (const float*)d_in[3];
  const float* Wk = (const float*)d_in[4];
  const float* Wv = (const float*)d_in[5];
  const float* bv = (const float*)d_in[6];
  const float* Wo = (const float*)d_in[7];
  const float* bo = (const float*)d_in[8];

  char* ws = (char*)d_ws;
  unsigned short* xb  = (unsigned short*)(ws);               // 16MB (reused for attn out)
  unsigned short* wqb = (unsigned short*)(ws + (16u << 20)); // Wq,Wk,Wv,Wo contiguous
  unsigned short* wob = wqb + (3u << 20);
  unsigned short* qb_ = (unsigned short*)(ws + (24u << 20)); // Q,K,V contiguous 16MB each
  unsigned short* kb_ = (unsigned short*)(ws + (40u << 20));
  unsigned short* vb_ = (unsigned short*)(ws + (56u << 20));

  cvt_all<<<2048, 256, 0, stream>>>(x, Wq, Wk, Wv, Wo, xb, wqb);

  gemm_qkv<<<dim3(24, MROWS / 128), 256, 0, stream>>>(xb, wqb, bq, bv, qb_);

  flash_attn<<<dim3(BATCH * NHEAD, 16), 256, 0, stream>>>(qb_, kb_, vb_, xb);

  gemm_out<<<dim3(NSTATE / 128, MROWS / 128), 256, 0, stream>>>(xb, wob, bo, (float*)d_out);
}

// Round 13
// 186.047 us; speedup vs baseline: 1.0355x; 1.0177x over previous
//
#include <hip/hip_runtime.h>
#include <stdint.h>

#define DEVI __device__ __forceinline__

typedef float        f32x4   __attribute__((ext_vector_type(4)));
typedef float        f32x16  __attribute__((ext_vector_type(16)));
typedef __bf16       bf16x8  __attribute__((ext_vector_type(8)));
typedef unsigned short u16x8 __attribute__((ext_vector_type(8)));
typedef uint32_t     u32x2   __attribute__((ext_vector_type(2)));
typedef uint32_t     u32x4   __attribute__((ext_vector_type(4)));

static constexpr int TSEQ   = 2048;
static constexpr int NSTATE = 1024;
static constexpr int NHEAD  = 16;
static constexpr int DHEAD  = 64;
static constexpr int BATCH  = 4;
static constexpr int MROWS  = BATCH * TSEQ;              // 8192
// Q epilogue scale: D^-0.5 * log2(e)  (whole softmax in exp2 domain)
static constexpr float QSCALE = 0.125f * 1.44269504088896340736f;
static constexpr float DEFER_THR = 8.0f * 1.44269504088896340736f;

DEVI unsigned short f2bf(float f) {
  union { float f; uint32_t u; } v; v.f = f;
  return (unsigned short)((v.u + 0x7fffu + ((v.u >> 16) & 1u)) >> 16);
}

DEVI uint32_t cvt_pk_bf16(float lo, float hi) {   // packs {lo,hi} -> 2xbf16 (RNE)
  uint32_t r;
  asm("v_cvt_pk_bf16_f32 %0, %1, %2" : "=v"(r) : "v"(lo), "v"(hi));
  return r;
}
DEVI float fexp2(float x) {                        // bare v_exp_f32 (D = 2^S0)
  float r;
  asm("v_exp_f32 %0, %1" : "=v"(r) : "v"(x));
  return r;
}

DEVI f32x4 mfma16(u16x8 a, u16x8 b, f32x4 c) {
  return __builtin_amdgcn_mfma_f32_16x16x32_bf16(
      __builtin_bit_cast(bf16x8, a), __builtin_bit_cast(bf16x8, b), c, 0, 0, 0);
}
DEVI f32x16 mfma32(u16x8 a, u16x8 b, f32x16 c) {
  return __builtin_amdgcn_mfma_f32_32x32x16_bf16(
      __builtin_bit_cast(bf16x8, a), __builtin_bit_cast(bf16x8, b), c, 0, 0, 0);
}

DEVI void gload_lds16(const void* g, void* l) {
  __builtin_amdgcn_global_load_lds(
      (const __attribute__((address_space(1))) void*)g,
      (__attribute__((address_space(3))) void*)l, 16, 0, 0);
}

// ---------------- f32 -> bf16 conversion: x + 4 weights, one launch ---------
__global__ void cvt_all(const float* __restrict__ x,
                        const float* __restrict__ w0, const float* __restrict__ w1,
                        const float* __restrict__ w2, const float* __restrict__ w3,
                        unsigned short* __restrict__ xb,
                        unsigned short* __restrict__ wb)   // wq..wo contiguous
{
  const int NX = (MROWS * NSTATE) / 4;           // 2^21 float4 groups for x
  const int NW = (NSTATE * NSTATE) / 4;          // 2^18 per weight
  const int total = NX + 4 * NW;
  int i = blockIdx.x * blockDim.x + threadIdx.x;
  const int stride = gridDim.x * blockDim.x;
  for (; i < total; i += stride) {
    const float* src;
    unsigned short* dst;
    int j;
    if (i < NX) { src = x; dst = xb; j = i; }
    else {
      const int k = i - NX, wi = k >> 18;
      src = (wi == 0) ? w0 : (wi == 1) ? w1 : (wi == 2) ? w2 : w3;
      dst = wb + ((size_t)wi << 20);
      j = k & (NW - 1);
    }
    const float4 f = ((const float4*)src)[j];
    ushort4 o;
    o.x = f2bf(f.x); o.y = f2bf(f.y); o.z = f2bf(f.z); o.w = f2bf(f.w);
    ((ushort4*)dst)[j] = o;
  }
}

// ---------------- fused QKV GEMM: grid (24, 64); x -> {weight, n-tile} --------
// wi 0: Q = (acc+bq)*QSCALE ; wi 1: K = acc ; wi 2: V = acc+bv
__global__ __launch_bounds__(256)
void gemm_qkv(const unsigned short* __restrict__ A,
              const unsigned short* __restrict__ Wqkv,
              const float* __restrict__ bq, const float* __restrict__ bv,
              unsigned short* __restrict__ Oqkv)
{
  __shared__ __align__(16) unsigned short As[128 * 32];
  __shared__ __align__(16) unsigned short Bs[128 * 32];
  const int t  = threadIdx.x;
  const int l  = t & 63, w = t >> 6;
  const int fr = l & 15, fq = l >> 4;
  const int wi = blockIdx.x >> 3;
  const int n0 = (blockIdx.x & 7) * 128;
  const int m0 = blockIdx.y * 128;
  const int wm = (w & 1) * 64, wn = (w >> 1) * 64;
  const unsigned short* Bw = Wqkv + ((size_t)wi << 20);
  unsigned short* Cq = Oqkv + ((size_t)wi << 23);

  f32x4 acc[4][4] = {};

  const int sr = t >> 2;
  const int sc = (t & 3) * 8;
  const unsigned short* ag = A  + (size_t)(m0 + sr) * NSTATE + sc;
  const unsigned short* bg = Bw + (size_t)(n0 + sr) * NSTATE + sc;
  unsigned short* lA0 = As + t * 8;
  unsigned short* lA1 = As + 2048 + t * 8;
  unsigned short* lB0 = Bs + t * 8;
  unsigned short* lB1 = Bs + 2048 + t * 8;

  for (int kt = 0; kt < NSTATE / 32; ++kt) {
    const int ko = kt * 32;
    gload_lds16(ag + ko,               lA0);
    gload_lds16(ag + 64 * NSTATE + ko, lA1);
    gload_lds16(bg + ko,               lB0);
    gload_lds16(bg + 64 * NSTATE + ko, lB1);
    __syncthreads();

    u16x8 a[4], b[4];
    #pragma unroll
    for (int i = 0; i < 4; ++i)
      a[i] = *(const u16x8*)(As + (wm + i * 16 + fr) * 32 + fq * 8);
    #pragma unroll
    for (int j = 0; j < 4; ++j)
      b[j] = *(const u16x8*)(Bs + (wn + j * 16 + fr) * 32 + fq * 8);
    #pragma unroll
    for (int i = 0; i < 4; ++i)
      #pragma unroll
      for (int j = 0; j < 4; ++j)
        acc[i][j] = mfma16(a[i], b[j], acc[i][j]);
    __syncthreads();
  }

  const int h = (n0 + wn) >> 6;
  #pragma unroll
  for (int j = 0; j < 4; ++j) {
    const int d = j * 16 + fr;
    const float bj = (wi == 1) ? 0.0f
                   : ((wi == 0) ? bq[n0 + wn + d] : bv[n0 + wn + d]);
    #pragma unroll
    for (int i = 0; i < 4; ++i) {
      #pragma unroll
      for (int r = 0; r < 4; ++r) {
        const int row = m0 + wm + i * 16 + fq * 4 + r;
        const int bb = row >> 11, tt = row & (TSEQ - 1);
        float v = acc[i][j][r] + bj;
        if (wi == 0) v *= QSCALE;
        Cq[(((size_t)(bb * NHEAD + h)) * TSEQ + tt) * DHEAD + d] = f2bf(v);
      }
    }
  }
}

// ---------------- output projection GEMM: C = A W^T + bo (f32 out) ----------
__global__ __launch_bounds__(256)
void gemm_out(const unsigned short* __restrict__ A,
              const unsigned short* __restrict__ Bw,
              const float* __restrict__ bias,
              float* __restrict__ Co)
{
  __shared__ __align__(16) unsigned short As[128 * 32];
  __shared__ __align__(16) unsigned short Bs[128 * 32];
  const int t  = threadIdx.x;
  const int l  = t & 63, w = t >> 6;
  const int fr = l & 15, fq = l >> 4;
  const int m0 = blockIdx.y * 128, n0 = blockIdx.x * 128;
  const int wm = (w & 1) * 64, wn = (w >> 1) * 64;

  f32x4 acc[4][4] = {};

  const int sr = t >> 2;
  const int sc = (t & 3) * 8;
  const unsigned short* ag = A  + (size_t)(m0 + sr) * NSTATE + sc;
  const unsigned short* bg = Bw + (size_t)(n0 + sr) * NSTATE + sc;
  unsigned short* lA0 = As + t * 8;
  unsigned short* lA1 = As + 2048 + t * 8;
  unsigned short* lB0 = Bs + t * 8;
  unsigned short* lB1 = Bs + 2048 + t * 8;

  for (int kt = 0; kt < NSTATE / 32; ++kt) {
    const int ko = kt * 32;
    gload_lds16(ag + ko,               lA0);
    gload_lds16(ag + 64 * NSTATE + ko, lA1);
    gload_lds16(bg + ko,               lB0);
    gload_lds16(bg + 64 * NSTATE + ko, lB1);
    __syncthreads();

    u16x8 a[4], b[4];
    #pragma unroll
    for (int i = 0; i < 4; ++i)
      a[i] = *(const u16x8*)(As + (wm + i * 16 + fr) * 32 + fq * 8);
    #pragma unroll
    for (int j = 0; j < 4; ++j)
      b[j] = *(const u16x8*)(Bs + (wn + j * 16 + fr) * 32 + fq * 8);
    #pragma unroll
    for (int i = 0; i < 4; ++i)
      #pragma unroll
      for (int j = 0; j < 4; ++j)
        acc[i][j] = mfma16(a[i], b[j], acc[i][j]);
    __syncthreads();
  }

  #pragma unroll
  for (int j = 0; j < 4; ++j) {
    const int col = n0 + wn + j * 16 + fr;
    const float bj = bias[col];
    #pragma unroll
    for (int i = 0; i < 4; ++i) {
      const int row0 = m0 + wm + i * 16 + fq * 4;
      #pragma unroll
      for (int r = 0; r < 4; ++r)
        Co[(size_t)(row0 + r) * NSTATE + col] = acc[i][j][r] + bj;
    }
  }
}

// ---------------- flash attention: 4 waves x 32 q-rows, 32x32x16 MFMA --------
// grid (64 heads, 16 q-tiles), block 256; qb = 15 - y (longest first).
// KVBLK=64, K/V double-buffered LDS (16B-XOR swizzle), T14 early-issue staging.
// S^T = mfma32(K, Q); exp2-domain softmax; cvt_pk + permlane32_swap for P.
// LDS fragment byte-offsets hoisted out of the k-loop (lane-constant).
__global__ __launch_bounds__(256)
void flash_attn(const unsigned short* __restrict__ Qg,
                const unsigned short* __restrict__ Kg,
                const unsigned short* __restrict__ Vg,
                unsigned short* __restrict__ O)
{
  const int bh = blockIdx.x;
  const int qb = 15 - (int)blockIdx.y;
  const int b  = bh >> 4, h = bh & 15;
  const int t  = threadIdx.x, lane = t & 63, w = t >> 6;   // w: 0..3
  const int lq = lane & 31, hi = lane >> 5;
  const size_t hoff = (size_t)bh * TSEQ * DHEAD;
  const unsigned short* Qp = Qg + hoff;
  const unsigned short* Kp = Kg + hoff;
  const unsigned short* Vp = Vg + hoff;

  __shared__ __align__(16) unsigned short Kb[2][64 * 64];
  __shared__ __align__(16) unsigned short Vb[2][64 * 64];   // V^T, swizzled octets

  const int qw   = qb * 128 + w * 32;        // wave's first q-row
  const int qrow = qw + lq;                  // this lane's q-row

  u16x8 qf[4];                               // Q[qrow][16c + hi*8 .. +7]
  #pragma unroll
  for (int c = 0; c < 4; ++c)
    qf[c] = *(const u16x8*)(Qp + (size_t)qrow * DHEAD + c * 16 + hi * 8);

  f32x16 oacc[2] = {};                       // O^T: col=q(lane), rows d-pattern
  float m_r = -1e30f, l_r = 0.0f;            // exp2-domain softmax state

  // hoisted per-lane LDS byte offsets (constant across iterations)
  const char* KbB = (const char*)&Kb[0][0];
  const char* VbB = (const char*)&Vb[0][0];
  int koff[4], voff[4];
  #pragma unroll
  for (int c = 0; c < 4; ++c) {
    koff[c] = lq * 128 + (((2 * c + hi) ^ (lane & 7)) << 4);
    voff[c] = lq * 128 + (((2 * c + hi) ^ (lq & 7)) << 4);
  }

  // staging assignments (256 threads)
  const int skr = t >> 2, skg = t & 3;       // K: row skr, 32B chunk skg
  const int svk2 = (t & 31) * 2;             // V: two adjacent k per thread
  const int svd  = (t >> 5) * 8;             // 8 d's per thread

  const int nt = (qb + 1) * 2;

  #define STAGE_V(buf, va, vb)                                              \
    do {                                                                    \
      const u32x4 vau = __builtin_bit_cast(u32x4, va);                      \
      const u32x4 vbu = __builtin_bit_cast(u32x4, vb);                      \
      _Pragma("unroll")                                                     \
      for (int j = 0; j < 4; ++j) {                                         \
        const uint32_t pe = __builtin_amdgcn_perm(vbu[j], vau[j], 0x05040100); \
        const uint32_t po = __builtin_amdgcn_perm(vbu[j], vau[j], 0x07060302); \
        *(uint32_t*)(&Vb[buf][(svd + 2 * j) * 64 + (svk2 ^ ((2 * j) << 3))]) = pe; \
        *(uint32_t*)(&Vb[buf][(svd + 2 * j + 1) * 64 + (svk2 ^ ((2 * j + 1) << 3))]) = po; \
      }                                                                     \
    } while (0)

  { // prologue: stage tile 0
    const u16x8 kr0 = *(const u16x8*)(Kp + (size_t)skr * DHEAD + skg * 16);
    const u16x8 kr1 = *(const u16x8*)(Kp + (size_t)skr * DHEAD + skg * 16 + 8);
    const u16x8 va  = *(const u16x8*)(Vp + (size_t)svk2 * DHEAD + svd);
    const u16x8 vb  = *(const u16x8*)(Vp + (size_t)(svk2 + 1) * DHEAD + svd);
    *(u16x8*)(&Kb[0][skr * 64 + (((skg * 2)     ^ (skr & 7)) << 3)]) = kr0;
    *(u16x8*)(&Kb[0][skr * 64 + (((skg * 2 + 1) ^ (skr & 7)) << 3)]) = kr1;
    STAGE_V(0, va, vb);
  }
  __syncthreads();

  for (int kt = 0; kt < nt; ++kt) {
    const int k0 = kt * 64;
    const int curB = (kt & 1) << 13;         // byte offset of current buffer
    const bool pre = (kt + 1 < nt);
    u16x8 krn0, krn1, van, vbn;
    if (pre) {                               // T14: issue next-tile loads early
      const int k0n = k0 + 64;
      krn0 = *(const u16x8*)(Kp + (size_t)(k0n + skr) * DHEAD + skg * 16);
      krn1 = *(const u16x8*)(Kp + (size_t)(k0n + skr) * DHEAD + skg * 16 + 8);
      van  = *(const u16x8*)(Vp + (size_t)(k0n + svk2) * DHEAD + svd);
      vbn  = *(const u16x8*)(Vp + (size_t)(k0n + svk2 + 1) * DHEAD + svd);
    }

    if (k0 < qw + 32) {                      // wave-active (not fully masked)
      // ---- QK^T: S^T[k][q], 2 x (32k) tiles, 4 K=16 chunks over D=64
      f32x16 s[2];
      __builtin_amdgcn_s_setprio(1);
      #pragma unroll
      for (int t32 = 0; t32 < 2; ++t32) {
        if (k0 + t32 * 32 < qw + 32) {
          f32x16 z = {};
          #pragma unroll
          for (int c = 0; c < 4; ++c) {
            const u16x8 kf = *(const u16x8*)(KbB + curB + koff[c] + t32 * 4096);
            z = mfma32(kf, qf[c], z);
          }
          s[t32] = z;
        } else {
          #pragma unroll
          for (int r = 0; r < 16; ++r) s[t32][r] = -1e30f;
        }
      }
      __builtin_amdgcn_s_setprio(0);
      if (k0 + 63 > qw) {                    // crossing: element causal mask
        #pragma unroll
        for (int t32 = 0; t32 < 2; ++t32)
          #pragma unroll
          for (int r = 0; r < 16; ++r) {
            const int kk = k0 + t32 * 32 + (r & 3) + 8 * (r >> 2) + 4 * hi;
            if (kk > qrow) s[t32][r] = -1e30f;
          }
      }

      // ---- softmax max: max3 tree + one cross-half shuffle
      float mx = fmaxf(s[0][14], s[0][15]);
      #pragma unroll
      for (int r = 0; r < 14; r += 2) mx = fmaxf(fmaxf(mx, s[0][r]), s[0][r + 1]);
      #pragma unroll
      for (int r = 0; r < 16; r += 2) mx = fmaxf(fmaxf(mx, s[1][r]), s[1][r + 1]);
      mx = fmaxf(mx, __shfl_xor(mx, 32));

      if (__any(mx > m_r + DEFER_THR)) {     // T13 defer-max
        const float mnew = fmaxf(m_r, mx);
        const float corr = fexp2(m_r - mnew);
        #pragma unroll
        for (int ds = 0; ds < 2; ++ds)
          #pragma unroll
          for (int r = 0; r < 16; ++r) oacc[ds][r] *= corr;
        l_r *= corr;
        m_r = mnew;
      }

      // ---- P = exp2(S - m): cvt_pk packing; l-sum in f32 (pre-rounding)
      float ps = 0.0f;
      uint32_t pk[2][8];
      #pragma unroll
      for (int t32 = 0; t32 < 2; ++t32)
        #pragma unroll
        for (int m2 = 0; m2 < 8; ++m2) {
          const float pa = fexp2(s[t32][2 * m2]     - m_r);
          const float pb = fexp2(s[t32][2 * m2 + 1] - m_r);
          ps += pa + pb;
          pk[t32][m2] = cvt_pk_bf16(pa, pb);
        }
      ps += __shfl_xor(ps, 32);
      l_r += ps;

      // ---- P frags: half-exchange via permlane32_swap (T12)
      uint32_t pf[2][2][4];
      #pragma unroll
      for (int t32 = 0; t32 < 2; ++t32)
        #pragma unroll
        for (int hf = 0; hf < 2; ++hf) {
          const u32x2 r02 = __builtin_amdgcn_permlane32_swap(
              pk[t32][hf * 4 + 0], pk[t32][hf * 4 + 2], false, false);
          const u32x2 r13 = __builtin_amdgcn_permlane32_swap(
              pk[t32][hf * 4 + 1], pk[t32][hf * 4 + 3], false, false);
          pf[t32][hf][0] = r02.x; pf[t32][hf][2] = r02.y;
          pf[t32][hf][1] = r13.x; pf[t32][hf][3] = r13.y;
        }

      // ---- PV: O^T += V^T * P^T, 4 K=16 chunks over the 64 k
      __builtin_amdgcn_s_setprio(1);
      #pragma unroll
      for (int c = 0; c < 4; ++c) {
        if (k0 + 16 * c < qw + 32) {         // wave-uniform causal chunk skip
          const u32x4 pw = {pf[c >> 1][c & 1][0], pf[c >> 1][c & 1][1],
                            pf[c >> 1][c & 1][2], pf[c >> 1][c & 1][3]};
          const u16x8 pv = __builtin_bit_cast(u16x8, pw);
          #pragma unroll
          for (int ds = 0; ds < 2; ++ds) {
            const u16x8 vf = *(const u16x8*)(VbB + curB + voff[c] + ds * 4096);
            oacc[ds] = mfma32(vf, pv, oacc[ds]);
          }
        }
      }
      __builtin_amdgcn_s_setprio(0);
    }

    if (pre) {                               // write-late into the other buffer
      const int nb = (kt & 1) ^ 1;
      *(u16x8*)(&Kb[nb][skr * 64 + (((skg * 2)     ^ (skr & 7)) << 3)]) = krn0;
      *(u16x8*)(&Kb[nb][skr * 64 + (((skg * 2 + 1) ^ (skr & 7)) << 3)]) = krn1;
      STAGE_V(nb, van, vbn);
    }
    __syncthreads();
  }

  // ---- epilogue: O[q][d] = oacc/l, paired u32 stores
  const float inv = 1.0f / l_r;
  const size_t base = ((size_t)(b * TSEQ + qrow)) * NSTATE + h * DHEAD;
  #pragma unroll
  for (int ds = 0; ds < 2; ++ds)
    #pragma unroll
    for (int m2 = 0; m2 < 8; ++m2) {
      const int d = ds * 32 + 2 * (m2 & 1) + 8 * (m2 >> 1) + 4 * hi;
      *(uint32_t*)(O + base + d) =
          cvt_pk_bf16(oacc[ds][2 * m2] * inv, oacc[ds][2 * m2 + 1] * inv);
    }
  #undef STAGE_V
}

// ---------------- launcher ----------------
extern "C" void kernel_launch(void* const* d_in, const int* in_sizes, int n_in,
                              void* d_out, int out_size, void* d_ws, size_t ws_size,
                              hipStream_t stream)
{
  (void)in_sizes; (void)n_in; (void)out_size; (void)ws_size;
  const float* x  = (const float*)d_in[0];
  const float* Wq = (const float*)d_in[2];
  const float* bq = (const float*)d_in[3];
  const float* Wk = (const float*)d_in[4];
  const float* Wv = (const float*)d_in[5];
  const float* bv = (const float*)d_in[6];
  const float* Wo = (const float*)d_in[7];
  const float* bo = (const float*)d_in[8];

  char* ws = (char*)d_ws;
  unsigned short* xb  = (unsigned short*)(ws);               // 16MB (reused for attn out)
  unsigned short* wqb = (unsigned short*)(ws + (16u << 20)); // Wq,Wk,Wv,Wo contiguous
  unsigned short* wob = wqb + (3u << 20);
  unsigned short* qb_ = (unsigned short*)(ws + (24u << 20)); // Q,K,V contiguous 16MB each
  unsigned short* kb_ = (unsigned short*)(ws + (40u << 20));
  unsigned short* vb_ = (unsigned short*)(ws + (56u << 20));

  cvt_all<<<2048, 256, 0, stream>>>(x, Wq, Wk, Wv, Wo, xb, wqb);

  gemm_qkv<<<dim3(24, MROWS / 128), 256, 0, stream>>>(xb, wqb, bq, bv, qb_);

  flash_attn<<<dim3(BATCH * NHEAD, 16), 256, 0, stream>>>(qb_, kb_, vb_, xb);

  gemm_out<<<dim3(NSTATE / 128, MROWS / 128), 256, 0, stream>>>(xb, wob, bo, (float*)d_out);
}